// Round 10
// baseline (140.926 us; speedup 1.0000x reference)
//
#include <hip/hip_runtime.h>

// ContactLoss R16: R15 (best, 122.3us) + triangle-record hoisting.
//  - prep node: computes per-tri 64B records (identical tri_pre arithmetic,
//    absmax-0.0 lineage) into ws + zeroes hit arrays (absorbs memset node).
//  - mega: raycast loop reads records at wave-uniform GLOBAL addresses
//    (L2-resident broadcast) — no LDS staging, no __syncthreads, no
//    redundant per-chunk tri_pre. Partition/atomics identical to R15.
//    Runtime ws_size guard falls back to the R15 staged path.
//  - reduce_fin: R15 verbatim (1 parity load/point; done-counter finalize).

#define RX 0.4395064455f
#define RY 0.617598629942f
#define RZ 0.652231566745f

#define MAXCHUNK_F4 256   // LDS float4 slots for the fallback staged path
#define PTS_PER_BLK 512   // 2 points per thread

struct Params {
    const float* hand_verts; const int* hand_faces;
    const float* obj_verts;  const int* obj_faces;
    const int* ovsplit; const int* ofsplit;
    float4* trecA;             // [B*Fh*4] pass-A tri records (useG path)
    float4* trecB;             // [B*Fo*4] pass-B tri records
    int* hitsA;                // [B*No] pass-A hit counts (atomic accum)
    int* hitsB;                // [B*Nh] pass-B hit counts (atomic accum)
    float* anchor_h; float* anchor_o;
    float* partials;           // [B*16*6] per-(batch, virtual-wave) partials
    unsigned int* done;
    float* out;
    int B, Nh, Fh, No, Fo;
    int pbA, CA, chunkA, blocksA;
    int pbB, CB, chunkB, blocksB;
    int useG;                  // 1 = global tri records, 0 = staged fallback
};

// ---------------------------------------------------------------------------
// Per-triangle precompute (absmax-0.0 lineage; valid folded into invdet=0 —
// R7/R9-validated bit-exact).
// ---------------------------------------------------------------------------
__device__ __forceinline__ void tri_pre_one(const float* __restrict__ vb,
                                            const int* __restrict__ f,
                                            float4* o) {
#pragma clang fp contract(off)
    int i0 = f[0], i1 = f[1], i2 = f[2];
    float v0x = vb[i0*3+0], v0y = vb[i0*3+1], v0z = vb[i0*3+2];
    float v1x = vb[i1*3+0], v1y = vb[i1*3+1], v1z = vb[i1*3+2];
    float v2x = vb[i2*3+0], v2y = vb[i2*3+1], v2z = vb[i2*3+2];
    float e1x = v1x - v0x, e1y = v1y - v0y, e1z = v1z - v0z;
    float e2x = v2x - v0x, e2y = v2y - v0y, e2z = v2z - v0z;
    float px = RY*e2z - RZ*e2y;
    float py = RZ*e2x - RX*e2z;
    float pz = RX*e2y - RY*e2x;
    float det = (e1x*px + e1y*py) + e1z*pz;       // ((a+b)+c) like np.sum
    float invdet = 1.0f / (det + 1e-8f);          // 0.1*TOL, IEEE div
    if (fabsf(det) < 1e-7f) invdet = 0.0f;        // parallel => no hit, exactly
    o[0] = make_float4(v0x, v0y, v0z, invdet);
    o[1] = make_float4(e1x, e1y, e1z, 0.0f);
    o[2] = make_float4(e2x, e2y, e2z, 0.0f);
    o[3] = make_float4(px,  py,  pz,  0.0f);
}

// One Möller–Trumbore test (expression tree identical to absmax-0.0 lineage).
__device__ __forceinline__ int mt_test(float qx, float qy, float qz,
                                       const float4& f0, const float4& f1,
                                       const float4& f2, const float4& f3) {
#pragma clang fp contract(off)
    float tvx = qx - f0.x, tvy = qy - f0.y, tvz = qz - f0.z;
    float u  = ((tvx*f3.x + tvy*f3.y) + tvz*f3.z) * f0.w;
    float qvx = tvy*f1.z - tvz*f1.y;
    float qvy = tvz*f1.x - tvx*f1.z;
    float qvz = tvx*f1.y - tvy*f1.x;
    float v  = ((qvx*RX + qvy*RY) + qvz*RZ) * f0.w;
    float tt = ((f2.x*qvx + f2.y*qvy) + f2.z*qvz) * f0.w;
    bool hit = (u > 0.0f) && (u < 1.0f) && (v > 0.0f) &&
               ((u + v) < 1.0f) && (tt > 1e-7f);
    return hit ? 1 : 0;
}

// ---------------------------------------------------------------------------
// prep: per-tri records to global + zero hit arrays (absorbs memset node).
// ---------------------------------------------------------------------------
__global__ __launch_bounds__(256) void prep(Params p) {
    int j = blockIdx.x * 256 + threadIdx.x;
    int nTriA = p.B * p.Fh;
    int nTriB = p.B * p.Fo;
    if (j < nTriA) {
        int b = j / p.Fh, t = j - b * p.Fh;
        tri_pre_one(p.hand_verts + (size_t)b * p.Nh * 3,
                    p.hand_faces + ((size_t)b * p.Fh + t) * 3,
                    p.trecA + (size_t)j * 4);
    } else if (j < nTriA + nTriB) {
        int k = j - nTriA;
        int b = k / p.Fo, t = k - b * p.Fo;
        tri_pre_one(p.obj_verts + (size_t)b * p.No * 3,
                    p.obj_faces + ((size_t)b * p.Fo + t) * 3,
                    p.trecB + (size_t)k * 4);
    }
    if (j < p.B * p.No) p.hitsA[j] = 0;       // grid covers both (tris > hits)
    if (j < p.B * p.Nh) p.hitsB[j] = 0;
}

// ---------------------------------------------------------------------------
// One raycast virtual block. useG: inner loop reads tri records at
// wave-uniform global addresses (no LDS, no barrier). Fallback: R15 staged.
// Wave-uniform __any(act2) dual/single selection (R9-proven).
// ---------------------------------------------------------------------------
__device__ __forceinline__ void raycast_vb(const Params& p, int vbid, int tid,
                                           float4* s_tri) {
#pragma clang fp contract(off)
    const float* pts; const float* tverts; const int* tfaces; int* slots;
    const float4* trec;
    int P, T, Nv, c, pb, b, chunk, tlim, plim;
    if (vbid < p.blocksA) {
        int per_b = p.pbA * p.CA;
        b  = vbid / per_b;
        int r = vbid - b * per_b;
        c  = r / p.pbA;
        pb = r - c * p.pbA;
        pts = p.obj_verts; tverts = p.hand_verts; tfaces = p.hand_faces;
        slots = p.hitsA; trec = p.trecA + (size_t)b * p.Fh * 4;
        P = p.No; T = p.Fh; Nv = p.Nh; chunk = p.chunkA;
        tlim = p.Fh; plim = min(p.No, p.ovsplit[b]);   // invalid pts never read
    } else {
        int j = vbid - p.blocksA;
        int per_b = p.pbB * p.CB;
        b  = j / per_b;
        int r = j - b * per_b;
        c  = r / p.pbB;
        pb = r - c * p.pbB;
        pts = p.hand_verts; tverts = p.obj_verts; tfaces = p.obj_faces;
        slots = p.hitsB; trec = p.trecB + (size_t)b * p.Fo * 4;
        P = p.Nh; T = p.Fo; Nv = p.No; chunk = p.chunkB;
        tlim = min(p.Fo, p.ofsplit[b]); plim = p.Nh;
    }

    int tStart = c * chunk;
    if (tStart >= tlim) return;               // block-uniform
    if (pb * PTS_PER_BLK >= plim) return;     // block-uniform
    int tEnd = min(tStart + chunk, tlim);

    if (!p.useG) {                            // fallback: stage into LDS
        int nTri = tEnd - tStart;
        if (tid < nTri) {
            int t = tStart + tid;
            tri_pre_one(tverts + (size_t)b * Nv * 3,
                        tfaces + ((size_t)b * T + t) * 3,
                        s_tri + (size_t)tid * 4);
        }
    }

    int p1 = pb * PTS_PER_BLK + tid;
    int p2 = p1 + 256;
    bool act1 = p1 < plim, act2 = p2 < plim;
    float q1x = 0.f, q1y = 0.f, q1z = 0.f;
    float q2x = 0.f, q2y = 0.f, q2z = 0.f;
    if (act1) {
        const float* q = pts + ((size_t)b * P + p1) * 3;
        q1x = q[0]; q1y = q[1]; q1z = q[2];
    }
    if (act2) {
        const float* q = pts + ((size_t)b * P + p2) * 3;
        q2x = q[0]; q2y = q[1]; q2z = q[2];
    }

    int cnt1 = 0, cnt2 = 0;
    if (p.useG) {
        if (!act1) return;                    // act1 false => act2 false
        const float4* __restrict__ tr = trec + (size_t)tStart * 4;
        int n = tEnd - tStart;
        if (__any(act2)) {
            for (int i = 0; i < n; ++i) {
                const float4 f0 = tr[(i<<2)+0];
                const float4 f1 = tr[(i<<2)+1];
                const float4 f2 = tr[(i<<2)+2];
                const float4 f3 = tr[(i<<2)+3];
                cnt1 += mt_test(q1x, q1y, q1z, f0, f1, f2, f3);
                cnt2 += mt_test(q2x, q2y, q2z, f0, f1, f2, f3);
            }
        } else {
            for (int i = 0; i < n; ++i) {
                const float4 f0 = tr[(i<<2)+0];
                const float4 f1 = tr[(i<<2)+1];
                const float4 f2 = tr[(i<<2)+2];
                const float4 f3 = tr[(i<<2)+3];
                cnt1 += mt_test(q1x, q1y, q1z, f0, f1, f2, f3);
            }
        }
    } else {
        __syncthreads();                      // staged fallback (R15 path)
        if (!act1) return;
        int n = tEnd - tStart;
        if (__any(act2)) {
            for (int i = 0; i < n; ++i) {
                const float4 f0 = s_tri[(i<<2)+0];
                const float4 f1 = s_tri[(i<<2)+1];
                const float4 f2 = s_tri[(i<<2)+2];
                const float4 f3 = s_tri[(i<<2)+3];
                cnt1 += mt_test(q1x, q1y, q1z, f0, f1, f2, f3);
                cnt2 += mt_test(q2x, q2y, q2z, f0, f1, f2, f3);
            }
        } else {
            for (int i = 0; i < n; ++i) {
                const float4 f0 = s_tri[(i<<2)+0];
                const float4 f1 = s_tri[(i<<2)+1];
                const float4 f2 = s_tri[(i<<2)+2];
                const float4 f3 = s_tri[(i<<2)+3];
                cnt1 += mt_test(q1x, q1y, q1z, f0, f1, f2, f3);
            }
        }
    }
    int* base = slots + (size_t)b * P;
    if (cnt1)         atomicAdd(&base[p1], cnt1);   // integer sum — exact
    if (act2 && cnt2) atomicAdd(&base[p2], cnt2);
}

// ---------------------------------------------------------------------------
// One argmin wave. Packed (dist<<32)|idx min => np.argmin tie-break.
// ---------------------------------------------------------------------------
__device__ __forceinline__ void min_one(const Params& p, int w, int lane) {
#pragma clang fp contract(off)
    int nHand = p.B * p.Nh;
    const float* refv; const float* loopv; int loopN; float* outp;
    if (w < nHand) {
        int b = w / p.Nh;
        int n = w - b * p.Nh;
        refv  = p.hand_verts + ((size_t)b * p.Nh + n) * 3;
        loopv = p.obj_verts + (size_t)b * p.No * 3;
        loopN = p.ovsplit[b];
        outp  = p.anchor_h + (size_t)b * p.Nh + n;
    } else {
        int j = w - nHand;
        int b = j / p.No;
        int m = j - b * p.No;
        if (m >= p.ovsplit[b]) return;
        refv  = p.obj_verts + ((size_t)b * p.No + m) * 3;
        loopv = p.hand_verts + (size_t)b * p.Nh * 3;
        loopN = p.Nh;
        outp  = p.anchor_o + (size_t)b * p.No + m;
    }
    float hx = refv[0], hy = refv[1], hz = refv[2];
    float rx = (hx*hx + hy*hy) + hz*hz;
    unsigned long long best = ~0ull;
    for (int m = lane; m < loopN; m += 64) {
        float ox = loopv[m*3+0], oy = loopv[m*3+1], oz = loopv[m*3+2];
        float ry = (ox*ox + oy*oy) + oz*oz;
        float zz = (hx*ox + hy*oy) + hz*oz;
        float d = (rx + ry) - 2.0f * zz;
        unsigned long long e = ((unsigned long long)__float_as_uint(d) << 32) | (unsigned)m;
        if (e < best) best = e;
    }
    for (int off = 32; off > 0; off >>= 1) {
        unsigned long long o = __shfl_xor(best, off, 64);
        if (o < best) best = o;
    }
    if (lane == 0) {
        int idx = (best == ~0ull) ? 0 : (int)(best & 0xffffffffu);
        const float* cv = loopv + (size_t)idx * 3;
        float dx = cv[0] - hx, dy = cv[1] - hy, dz = cv[2] - hz;
        *outp = sqrtf((dx*dx + dy*dy) + dz*dz);
    }
}

// ---------------------------------------------------------------------------
// mega: [raycast VBs | argmin blocks] — no tail sync; resets done counter.
// ---------------------------------------------------------------------------
__global__ __launch_bounds__(256) void mega(Params p) {
    __shared__ float4 s_tri[MAXCHUNK_F4];
    const int tid = threadIdx.x;
    const int bid = blockIdx.x;
    if (bid == 0 && tid == 0) *p.done = 0u;   // visible to reduce_fin at boundary
    const int nRay = p.blocksA + p.blocksB;
    if (bid < nRay) {
        raycast_vb(p, bid, tid, s_tri);
    } else {
        int w = (bid - nRay) * 4 + (tid >> 6);
        if (w < p.B * (p.Nh + p.No)) min_one(p, w, tid & 63);
    }
}

// ---------------------------------------------------------------------------
// reduce_fin: 128 single-wave blocks (R15 verbatim). Parity = 1 load/point.
// ---------------------------------------------------------------------------
__global__ __launch_bounds__(64) void reduce_fin(Params p) {
    const int r    = blockIdx.x;
    const int b    = r >> 4;
    const int wv   = r & 15;
    const int lane = threadIdx.x;
    const int vt   = wv * 64 + lane;          // virtual tid 0..1023
    float s0=0.f,s1=0.f,s2=0.f,s3=0.f,s4=0.f,s5=0.f;

    for (int n = vt; n < p.Nh; n += 1024) {
        int par = p.hitsB[(size_t)b * p.Nh + n];
        bool ext = (par & 1) == 0;
        float val = 25.0f * tanhf(p.anchor_h[(size_t)b*p.Nh + n] / 25.0f);
        if (ext) { s0 += val; s1 += 1.0f; } else { s2 += val; s3 += 1.0f; }
    }
    int split = p.ovsplit[b];
    for (int m = vt; m < split; m += 1024) {
        int par = p.hitsA[(size_t)b * p.No + m];
        if (par & 1) {                                   // interior & valid
            s4 += 25.0f * tanhf(p.anchor_o[(size_t)b*p.No + m] / 25.0f);
            s5 += 1.0f;
        }
    }
    for (int off = 32; off > 0; off >>= 1) {
        s0 += __shfl_xor(s0, off, 64);
        s1 += __shfl_xor(s1, off, 64);
        s2 += __shfl_xor(s2, off, 64);
        s3 += __shfl_xor(s3, off, 64);
        s4 += __shfl_xor(s4, off, 64);
        s5 += __shfl_xor(s5, off, 64);
    }

    __shared__ bool s_last;
    if (lane == 0) {
        float* q = p.partials + ((size_t)(b * 16 + wv)) * 6;
        q[0]=s0; q[1]=s1; q[2]=s2; q[3]=s3; q[4]=s4; q[5]=s5;
        __threadfence();                     // release partials
        unsigned int old = atomicAdd(p.done, 1u);
        s_last = (old == (unsigned int)(gridDim.x - 1));
    }
    __syncthreads();
    if (!s_last) return;
    __threadfence();                         // acquire others' partials

    __shared__ float s_red[16][6];
    if (lane < p.B && lane < 16) {
        int bb = lane;
        float t0=0.f,t1=0.f,t2=0.f,t3=0.f,t4=0.f,t5=0.f;
        for (int w2 = 0; w2 < 16; ++w2) {     // same wave order as old loop
            const float* q = p.partials + ((size_t)(bb * 16 + w2)) * 6;
            t0 += q[0]; t1 += q[1]; t2 += q[2];
            t3 += q[3]; t4 += q[4]; t5 += q[5];
        }
        p.out[2 + bb]  = (t1 > 0.f) ? t0 / fmaxf(t1, 1.f) : 0.f;
        float ph       = (t3 > 0.f) ? t2 / fmaxf(t3, 1.f) : 0.f;
        float po       = (t5 > 0.f) ? t4 / fmaxf(t5, 1.f) : 0.f;
        p.out[10 + bb] = ph + po;
        s_red[bb][0]=t0; s_red[bb][1]=t1; s_red[bb][2]=t2;
        s_red[bb][3]=t3; s_red[bb][4]=t4; s_red[bb][5]=t5;
    }
    __syncthreads();
    if (lane == 0) {
        float sm=0.f,cm=0.f,sph=0.f,cph=0.f,spo=0.f,cpo=0.f;
        for (int bb = 0; bb < p.B; ++bb) {    // same batch order as old final
            sm  += s_red[bb][0]; cm  += s_red[bb][1]; sph += s_red[bb][2];
            cph += s_red[bb][3]; spo += s_red[bb][4]; cpo += s_red[bb][5];
        }
        float missed = (cm  > 0.f) ? sm  / fmaxf(cm , 1.f) : 0.f;
        float ph     = (cph > 0.f) ? sph / fmaxf(cph, 1.f) : 0.f;
        float po     = (cpo > 0.f) ? spo / fmaxf(cpo, 1.f) : 0.f;
        p.out[0] = missed;
        p.out[1] = ph + po;
    }
}

// ---------------------------------------------------------------------------
extern "C" void kernel_launch(void* const* d_in, const int* in_sizes, int n_in,
                              void* d_out, int out_size, void* d_ws, size_t ws_size,
                              hipStream_t stream) {
    Params p;
    p.hand_verts = (const float*)d_in[0];
    p.hand_faces = (const int*)d_in[1];
    p.obj_verts  = (const float*)d_in[2];
    p.obj_faces  = (const int*)d_in[3];
    p.ovsplit    = (const int*)d_in[4];
    p.ofsplit    = (const int*)d_in[5];
    p.out        = (float*)d_out;

    p.B  = in_sizes[4];
    p.Nh = in_sizes[0] / (3 * p.B);
    p.Fh = in_sizes[1] / (3 * p.B);
    p.No = in_sizes[2] / (3 * p.B);
    p.Fo = in_sizes[3] / (3 * p.B);

    p.CA = 32; p.CB = 64;
    p.chunkA = (p.Fh + p.CA - 1) / p.CA;       // 49 for Fh=1538
    p.chunkB = (p.Fo + p.CB - 1) / p.CB;       // 63 for Fo=4000
    p.pbA = (p.No + PTS_PER_BLK - 1) / PTS_PER_BLK;   // 4
    p.pbB = (p.Nh + PTS_PER_BLK - 1) / PTS_PER_BLK;   // 2
    p.blocksA = p.pbA * p.CA * p.B;            // 1024
    p.blocksB = p.pbB * p.CB * p.B;            // 1024

    // Size check: global-record path needs ~2.9MB of ws; else staged fallback.
    size_t needG = ((size_t)p.B * (p.Fh + p.Fo) * 4 * sizeof(float4)) +
                   ((size_t)p.B * (p.No + p.Nh) * sizeof(int)) +
                   ((size_t)p.B * (p.Nh + p.No) * sizeof(float)) +
                   ((size_t)p.B * 16 * 6 * sizeof(float)) + 4096;
    p.useG = (ws_size >= needG) ? 1 : 0;

    char* ws = (char*)d_ws;
    size_t off = 0;
    auto alloc = [&](size_t bytes) -> void* {
        void* q = ws + off;
        off = (off + bytes + 255) & ~(size_t)255;
        return q;
    };
    if (p.useG) {
        p.trecA = (float4*)alloc((size_t)p.B * p.Fh * 4 * sizeof(float4));
        p.trecB = (float4*)alloc((size_t)p.B * p.Fo * 4 * sizeof(float4));
    } else {
        p.trecA = nullptr; p.trecB = nullptr;
    }
    size_t hitsOff = off;
    p.hitsA    = (int*)   alloc((size_t)p.B * p.No * sizeof(int));
    p.hitsB    = (int*)   alloc((size_t)p.B * p.Nh * sizeof(int));
    size_t hitsBytes = off - hitsOff;
    p.anchor_h = (float*) alloc((size_t)p.B * p.Nh * sizeof(float));
    p.anchor_o = (float*) alloc((size_t)p.B * p.No * sizeof(float));
    p.partials = (float*) alloc((size_t)p.B * 16 * 6 * sizeof(float));
    p.done     = (unsigned int*)alloc(sizeof(unsigned int));

    int totalMin   = p.B * (p.Nh + p.No);
    int nMinBlocks = (totalMin + 3) / 4;       // 4 argmin waves per block
    int grid = p.blocksA + p.blocksB + nMinBlocks;

    if (p.useG) {
        int nPrep = (p.B * (p.Fh + p.Fo) + 255) / 256;
        prep<<<nPrep, 256, 0, stream>>>(p);    // records + hits zeroing
    } else {
        hipMemsetAsync((void*)p.hitsA, 0, hitsBytes, stream);
    }
    mega<<<grid, 256, 0, stream>>>(p);
    reduce_fin<<<p.B * 16, 64, 0, stream>>>(p);
}

// Round 13
// 125.024 us; speedup vs baseline: 1.1272x; 1.1272x over previous
//
#include <hip/hip_runtime.h>

// ContactLoss R17 (3rd submit — prior two runs died at container acquire,
// not in the kernel): R15 (best, 122.3us) + PAIRED argmin waves.
//  - R16 falsified global tri records (FETCH 2.4x, VALUBusy 72->52, +19us):
//    LDS staging is the right form. Full revert to R15's mega raycast.
//  - argmin: 2 ref points per wave, same (batch, side) => one pass over
//    loopv serves both packed mins (loads halved; wave count halved).
//    Bit-exact: identical per-ref expression/visit order/butterfly; min is
//    an exact total order. Pair (i, i+ceil(N/2)); guarded writes.
//  - reduce_fin: R15 verbatim (1 parity load/point; done-counter finalize).

#define RX 0.4395064455f
#define RY 0.617598629942f
#define RZ 0.652231566745f

#define MAXCHUNK_F4 256   // LDS float4 slots; >= max(chunkA,chunkB)*4 (252)
#define PTS_PER_BLK 512   // 2 points per thread

struct Params {
    const float* hand_verts; const int* hand_faces;
    const float* obj_verts;  const int* obj_faces;
    const int* ovsplit; const int* ofsplit;
    int* hitsA;                // [B*No] pass-A hit counts (atomic accum)
    int* hitsB;                // [B*Nh] pass-B hit counts (atomic accum)
    float* anchor_h; float* anchor_o;
    float* partials;           // [B*16*6] per-(batch, virtual-wave) partials
    unsigned int* done;
    float* out;
    int B, Nh, Fh, No, Fo;
    int pbA, CA, chunkA, blocksA;
    int pbB, CB, chunkB, blocksB;
};

// ---------------------------------------------------------------------------
// Per-triangle precompute (absmax-0.0 lineage; valid folded into invdet=0 —
// R7/R9-validated bit-exact).
// ---------------------------------------------------------------------------
__device__ __forceinline__ void tri_pre_one(const float* __restrict__ vb,
                                            const int* __restrict__ f,
                                            float4* o) {
#pragma clang fp contract(off)
    int i0 = f[0], i1 = f[1], i2 = f[2];
    float v0x = vb[i0*3+0], v0y = vb[i0*3+1], v0z = vb[i0*3+2];
    float v1x = vb[i1*3+0], v1y = vb[i1*3+1], v1z = vb[i1*3+2];
    float v2x = vb[i2*3+0], v2y = vb[i2*3+1], v2z = vb[i2*3+2];
    float e1x = v1x - v0x, e1y = v1y - v0y, e1z = v1z - v0z;
    float e2x = v2x - v0x, e2y = v2y - v0y, e2z = v2z - v0z;
    float px = RY*e2z - RZ*e2y;
    float py = RZ*e2x - RX*e2z;
    float pz = RX*e2y - RY*e2x;
    float det = (e1x*px + e1y*py) + e1z*pz;       // ((a+b)+c) like np.sum
    float invdet = 1.0f / (det + 1e-8f);          // 0.1*TOL, IEEE div
    if (fabsf(det) < 1e-7f) invdet = 0.0f;        // parallel => no hit, exactly
    o[0] = make_float4(v0x, v0y, v0z, invdet);
    o[1] = make_float4(e1x, e1y, e1z, 0.0f);
    o[2] = make_float4(e2x, e2y, e2z, 0.0f);
    o[3] = make_float4(px,  py,  pz,  0.0f);
}

// One Möller–Trumbore test (expression tree identical to absmax-0.0 lineage).
__device__ __forceinline__ int mt_test(float qx, float qy, float qz,
                                       const float4& f0, const float4& f1,
                                       const float4& f2, const float4& f3) {
#pragma clang fp contract(off)
    float tvx = qx - f0.x, tvy = qy - f0.y, tvz = qz - f0.z;
    float u  = ((tvx*f3.x + tvy*f3.y) + tvz*f3.z) * f0.w;
    float qvx = tvy*f1.z - tvz*f1.y;
    float qvy = tvz*f1.x - tvx*f1.z;
    float qvz = tvx*f1.y - tvy*f1.x;
    float v  = ((qvx*RX + qvy*RY) + qvz*RZ) * f0.w;
    float tt = ((f2.x*qvx + f2.y*qvy) + f2.z*qvz) * f0.w;
    bool hit = (u > 0.0f) && (u < 1.0f) && (v > 0.0f) &&
               ((u + v) < 1.0f) && (tt > 1e-7f);
    return hit ? 1 : 0;
}

// ---------------------------------------------------------------------------
// One raycast virtual block (R15 verbatim): chunk staged in LDS, 2 points
// per thread, wave-uniform __any(act2) selection, atomic count accumulate.
// ---------------------------------------------------------------------------
__device__ __forceinline__ void raycast_vb(const Params& p, int vbid, int tid,
                                           float4* s_tri) {
#pragma clang fp contract(off)
    const float* pts; const float* tverts; const int* tfaces; int* slots;
    int P, T, Nv, c, pb, b, chunk, tlim, plim;
    if (vbid < p.blocksA) {
        int per_b = p.pbA * p.CA;
        b  = vbid / per_b;
        int r = vbid - b * per_b;
        c  = r / p.pbA;
        pb = r - c * p.pbA;
        pts = p.obj_verts; tverts = p.hand_verts; tfaces = p.hand_faces;
        slots = p.hitsA;
        P = p.No; T = p.Fh; Nv = p.Nh; chunk = p.chunkA;
        tlim = p.Fh; plim = min(p.No, p.ovsplit[b]);   // invalid pts never read
    } else {
        int j = vbid - p.blocksA;
        int per_b = p.pbB * p.CB;
        b  = j / per_b;
        int r = j - b * per_b;
        c  = r / p.pbB;
        pb = r - c * p.pbB;
        pts = p.hand_verts; tverts = p.obj_verts; tfaces = p.obj_faces;
        slots = p.hitsB;
        P = p.Nh; T = p.Fo; Nv = p.No; chunk = p.chunkB;
        tlim = min(p.Fo, p.ofsplit[b]); plim = p.Nh;
    }

    int tStart = c * chunk;
    if (tStart >= tlim) return;               // block-uniform
    if (pb * PTS_PER_BLK >= plim) return;     // block-uniform
    int nTri = min(tStart + chunk, tlim) - tStart;

    if (tid < nTri) {
        int t = tStart + tid;
        tri_pre_one(tverts + (size_t)b * Nv * 3,
                    tfaces + ((size_t)b * T + t) * 3,
                    s_tri + (size_t)tid * 4);
    }

    int p1 = pb * PTS_PER_BLK + tid;
    int p2 = p1 + 256;
    bool act1 = p1 < plim, act2 = p2 < plim;
    float q1x = 0.f, q1y = 0.f, q1z = 0.f;
    float q2x = 0.f, q2y = 0.f, q2z = 0.f;
    if (act1) {
        const float* q = pts + ((size_t)b * P + p1) * 3;
        q1x = q[0]; q1y = q[1]; q1z = q[2];
    }
    if (act2) {
        const float* q = pts + ((size_t)b * P + p2) * 3;
        q2x = q[0]; q2y = q[1]; q2z = q[2];
    }
    __syncthreads();

    if (!act1) return;                        // act1 false => act2 false
    int cnt1 = 0, cnt2 = 0;
    if (__any(act2)) {
        for (int i = 0; i < nTri; ++i) {
            const float4 f0 = s_tri[(i<<2)+0];
            const float4 f1 = s_tri[(i<<2)+1];
            const float4 f2 = s_tri[(i<<2)+2];
            const float4 f3 = s_tri[(i<<2)+3];
            cnt1 += mt_test(q1x, q1y, q1z, f0, f1, f2, f3);
            cnt2 += mt_test(q2x, q2y, q2z, f0, f1, f2, f3);
        }
    } else {
        for (int i = 0; i < nTri; ++i) {
            const float4 f0 = s_tri[(i<<2)+0];
            const float4 f1 = s_tri[(i<<2)+1];
            const float4 f2 = s_tri[(i<<2)+2];
            const float4 f3 = s_tri[(i<<2)+3];
            cnt1 += mt_test(q1x, q1y, q1z, f0, f1, f2, f3);
        }
    }
    int* base = slots + (size_t)b * P;
    if (cnt1)         atomicAdd(&base[p1], cnt1);   // integer sum — exact
    if (act2 && cnt2) atomicAdd(&base[p2], cnt2);
}

// ---------------------------------------------------------------------------
// One PAIRED argmin wave: 2 ref points of the same (batch, side), one pass
// over loopv. Packed (dist<<32)|idx min => np.argmin tie-break, per ref.
// ---------------------------------------------------------------------------
__device__ __forceinline__ void min_pair(const Params& p, int w, int lane) {
#pragma clang fp contract(off)
    const int hA = (p.Nh + 1) >> 1, hB = (p.No + 1) >> 1;
    const int nHandW = p.B * hA;
    const float* loopv; int loopN;
    const float* ref1 = nullptr; const float* ref2 = nullptr;
    float* out1 = nullptr; float* out2 = nullptr;
    if (w < nHandW) {
        int b = w / hA, n1 = w - b * hA, n2 = n1 + hA;
        ref1 = p.hand_verts + ((size_t)b * p.Nh + n1) * 3;
        out1 = p.anchor_h + (size_t)b * p.Nh + n1;
        if (n2 < p.Nh) {
            ref2 = p.hand_verts + ((size_t)b * p.Nh + n2) * 3;
            out2 = p.anchor_h + (size_t)b * p.Nh + n2;
        }
        loopv = p.obj_verts + (size_t)b * p.No * 3;
        loopN = p.ovsplit[b];
    } else {
        int j = w - nHandW;
        int b = j / hB, m1 = j - b * hB, m2 = m1 + hB;
        int split = p.ovsplit[b];
        if (m1 < split) {
            ref1 = p.obj_verts + ((size_t)b * p.No + m1) * 3;
            out1 = p.anchor_o + (size_t)b * p.No + m1;
        }
        if (m2 < p.No && m2 < split) {
            ref2 = p.obj_verts + ((size_t)b * p.No + m2) * 3;
            out2 = p.anchor_o + (size_t)b * p.No + m2;
        }
        if (!ref1 && !ref2) return;
        loopv = p.hand_verts + (size_t)b * p.Nh * 3;
        loopN = p.Nh;
    }
    float h1x=0.f,h1y=0.f,h1z=0.f,r1=0.f, h2x=0.f,h2y=0.f,h2z=0.f,r2=0.f;
    if (ref1) { h1x=ref1[0]; h1y=ref1[1]; h1z=ref1[2];
                r1=(h1x*h1x + h1y*h1y) + h1z*h1z; }
    if (ref2) { h2x=ref2[0]; h2y=ref2[1]; h2z=ref2[2];
                r2=(h2x*h2x + h2y*h2y) + h2z*h2z; }
    unsigned long long b1 = ~0ull, b2 = ~0ull;
    for (int m = lane; m < loopN; m += 64) {
        float ox = loopv[m*3+0], oy = loopv[m*3+1], oz = loopv[m*3+2];
        float ry = (ox*ox + oy*oy) + oz*oz;
        float zz1 = (h1x*ox + h1y*oy) + h1z*oz;
        float d1 = (r1 + ry) - 2.0f * zz1;          // token-identical expr
        unsigned long long e1 =
            ((unsigned long long)__float_as_uint(d1) << 32) | (unsigned)m;
        if (e1 < b1) b1 = e1;
        float zz2 = (h2x*ox + h2y*oy) + h2z*oz;
        float d2 = (r2 + ry) - 2.0f * zz2;
        unsigned long long e2 =
            ((unsigned long long)__float_as_uint(d2) << 32) | (unsigned)m;
        if (e2 < b2) b2 = e2;
    }
    for (int off = 32; off > 0; off >>= 1) {
        unsigned long long o1 = __shfl_xor(b1, off, 64);
        if (o1 < b1) b1 = o1;
        unsigned long long o2 = __shfl_xor(b2, off, 64);
        if (o2 < b2) b2 = o2;
    }
    if (lane == 0) {
        if (out1) {
            int idx = (b1 == ~0ull) ? 0 : (int)(b1 & 0xffffffffu);
            const float* cv = loopv + (size_t)idx * 3;
            float dx = cv[0] - h1x, dy = cv[1] - h1y, dz = cv[2] - h1z;
            *out1 = sqrtf((dx*dx + dy*dy) + dz*dz);
        }
        if (out2) {
            int idx = (b2 == ~0ull) ? 0 : (int)(b2 & 0xffffffffu);
            const float* cv = loopv + (size_t)idx * 3;
            float dx = cv[0] - h2x, dy = cv[1] - h2y, dz = cv[2] - h2z;
            *out2 = sqrtf((dx*dx + dy*dy) + dz*dz);
        }
    }
}

// ---------------------------------------------------------------------------
// mega: [raycast VBs | paired argmin blocks] — resets done counter.
// ---------------------------------------------------------------------------
__global__ __launch_bounds__(256) void mega(Params p) {
    __shared__ float4 s_tri[MAXCHUNK_F4];
    const int tid = threadIdx.x;
    const int bid = blockIdx.x;
    if (bid == 0 && tid == 0) *p.done = 0u;   // visible to reduce_fin at boundary
    const int nRay = p.blocksA + p.blocksB;
    if (bid < nRay) {
        raycast_vb(p, bid, tid, s_tri);
    } else {
        int hA = (p.Nh + 1) >> 1, hB = (p.No + 1) >> 1;
        int w = (bid - nRay) * 4 + (tid >> 6);
        if (w < p.B * (hA + hB)) min_pair(p, w, tid & 63);
    }
}

// ---------------------------------------------------------------------------
// reduce_fin: 128 single-wave blocks (R15 verbatim). Parity = 1 load/point.
// ---------------------------------------------------------------------------
__global__ __launch_bounds__(64) void reduce_fin(Params p) {
    const int r    = blockIdx.x;
    const int b    = r >> 4;
    const int wv   = r & 15;
    const int lane = threadIdx.x;
    const int vt   = wv * 64 + lane;          // virtual tid 0..1023
    float s0=0.f,s1=0.f,s2=0.f,s3=0.f,s4=0.f,s5=0.f;

    for (int n = vt; n < p.Nh; n += 1024) {
        int par = p.hitsB[(size_t)b * p.Nh + n];
        bool ext = (par & 1) == 0;
        float val = 25.0f * tanhf(p.anchor_h[(size_t)b*p.Nh + n] / 25.0f);
        if (ext) { s0 += val; s1 += 1.0f; } else { s2 += val; s3 += 1.0f; }
    }
    int split = p.ovsplit[b];
    for (int m = vt; m < split; m += 1024) {
        int par = p.hitsA[(size_t)b * p.No + m];
        if (par & 1) {                                   // interior & valid
            s4 += 25.0f * tanhf(p.anchor_o[(size_t)b*p.No + m] / 25.0f);
            s5 += 1.0f;
        }
    }
    for (int off = 32; off > 0; off >>= 1) {
        s0 += __shfl_xor(s0, off, 64);
        s1 += __shfl_xor(s1, off, 64);
        s2 += __shfl_xor(s2, off, 64);
        s3 += __shfl_xor(s3, off, 64);
        s4 += __shfl_xor(s4, off, 64);
        s5 += __shfl_xor(s5, off, 64);
    }

    __shared__ bool s_last;
    if (lane == 0) {
        float* q = p.partials + ((size_t)(b * 16 + wv)) * 6;
        q[0]=s0; q[1]=s1; q[2]=s2; q[3]=s3; q[4]=s4; q[5]=s5;
        __threadfence();                     // release partials
        unsigned int old = atomicAdd(p.done, 1u);
        s_last = (old == (unsigned int)(gridDim.x - 1));
    }
    __syncthreads();
    if (!s_last) return;
    __threadfence();                         // acquire others' partials

    __shared__ float s_red[16][6];
    if (lane < p.B && lane < 16) {
        int bb = lane;
        float t0=0.f,t1=0.f,t2=0.f,t3=0.f,t4=0.f,t5=0.f;
        for (int w2 = 0; w2 < 16; ++w2) {     // same wave order as old loop
            const float* q = p.partials + ((size_t)(bb * 16 + w2)) * 6;
            t0 += q[0]; t1 += q[1]; t2 += q[2];
            t3 += q[3]; t4 += q[4]; t5 += q[5];
        }
        p.out[2 + bb]  = (t1 > 0.f) ? t0 / fmaxf(t1, 1.f) : 0.f;
        float ph       = (t3 > 0.f) ? t2 / fmaxf(t3, 1.f) : 0.f;
        float po       = (t5 > 0.f) ? t4 / fmaxf(t5, 1.f) : 0.f;
        p.out[10 + bb] = ph + po;
        s_red[bb][0]=t0; s_red[bb][1]=t1; s_red[bb][2]=t2;
        s_red[bb][3]=t3; s_red[bb][4]=t4; s_red[bb][5]=t5;
    }
    __syncthreads();
    if (lane == 0) {
        float sm=0.f,cm=0.f,sph=0.f,cph=0.f,spo=0.f,cpo=0.f;
        for (int bb = 0; bb < p.B; ++bb) {    // same batch order as old final
            sm  += s_red[bb][0]; cm  += s_red[bb][1]; sph += s_red[bb][2];
            cph += s_red[bb][3]; spo += s_red[bb][4]; cpo += s_red[bb][5];
        }
        float missed = (cm  > 0.f) ? sm  / fmaxf(cm , 1.f) : 0.f;
        float ph     = (cph > 0.f) ? sph / fmaxf(cph, 1.f) : 0.f;
        float po     = (cpo > 0.f) ? spo / fmaxf(cpo, 1.f) : 0.f;
        p.out[0] = missed;
        p.out[1] = ph + po;
    }
}

// ---------------------------------------------------------------------------
extern "C" void kernel_launch(void* const* d_in, const int* in_sizes, int n_in,
                              void* d_out, int out_size, void* d_ws, size_t ws_size,
                              hipStream_t stream) {
    Params p;
    p.hand_verts = (const float*)d_in[0];
    p.hand_faces = (const int*)d_in[1];
    p.obj_verts  = (const float*)d_in[2];
    p.obj_faces  = (const int*)d_in[3];
    p.ovsplit    = (const int*)d_in[4];
    p.ofsplit    = (const int*)d_in[5];
    p.out        = (float*)d_out;

    p.B  = in_sizes[4];
    p.Nh = in_sizes[0] / (3 * p.B);
    p.Fh = in_sizes[1] / (3 * p.B);
    p.No = in_sizes[2] / (3 * p.B);
    p.Fo = in_sizes[3] / (3 * p.B);

    p.CA = 32; p.CB = 64;
    p.chunkA = (p.Fh + p.CA - 1) / p.CA;       // 49 for Fh=1538
    p.chunkB = (p.Fo + p.CB - 1) / p.CB;       // 63 for Fo=4000
    p.pbA = (p.No + PTS_PER_BLK - 1) / PTS_PER_BLK;   // 4
    p.pbB = (p.Nh + PTS_PER_BLK - 1) / PTS_PER_BLK;   // 2
    p.blocksA = p.pbA * p.CA * p.B;            // 1024
    p.blocksB = p.pbB * p.CB * p.B;            // 1024

    char* ws = (char*)d_ws;
    size_t off = 0;
    auto alloc = [&](size_t bytes) -> void* {
        void* q = ws + off;
        off = (off + bytes + 255) & ~(size_t)255;
        return q;
    };
    size_t hitsOff = off;
    p.hitsA    = (int*)   alloc((size_t)p.B * p.No * sizeof(int));
    p.hitsB    = (int*)   alloc((size_t)p.B * p.Nh * sizeof(int));
    size_t hitsBytes = off - hitsOff;          // contiguous span, one memset
    p.anchor_h = (float*) alloc((size_t)p.B * p.Nh * sizeof(float));
    p.anchor_o = (float*) alloc((size_t)p.B * p.No * sizeof(float));
    p.partials = (float*) alloc((size_t)p.B * 16 * 6 * sizeof(float));
    p.done     = (unsigned int*)alloc(sizeof(unsigned int));

    int hA = (p.Nh + 1) / 2, hB = (p.No + 1) / 2;
    int totalMin   = p.B * (hA + hB);          // paired argmin waves
    int nMinBlocks = (totalMin + 3) / 4;       // 4 argmin waves per block
    int grid = p.blocksA + p.blocksB + nMinBlocks;

    hipMemsetAsync((void*)p.hitsA, 0, hitsBytes, stream);
    mega<<<grid, 256, 0, stream>>>(p);
    reduce_fin<<<p.B * 16, 64, 0, stream>>>(p);
}

// Round 14
// 124.611 us; speedup vs baseline: 1.1309x; 1.0033x over previous
//
#include <hip/hip_runtime.h>

// ContactLoss R18 = R15 VERBATIM (best verified: 122.3us, absmax 0.0).
// Terminal consolidation. Ladder: 133.7 (R6 baseline) -> 122.3 (R15).
//  - mega (61us): 2048 heavy raycast blocks (CA=32/CB=64, 4KB LDS chunks,
//    VGPR 32), dual-point loop with wave-uniform __any(act2) selection,
//    valid folded into invdet=0, integer atomicAdd hit accumulation.
//  - reduce_fin (~3us): 128 single-wave blocks, 1 parity load/point,
//    (batch, virtual-wave) bit-exact tree, done-counter + fence finalize.
//  - Falsified alternatives: coop fusion (R7), 4pt/low-occ (R10/R13),
//    per-lane transpose (R12), global tri records (R16), paired argmin
//    (R17, null — argmin already hidden under raycast).
//  - Remaining wall: ~44us mandatory VALU issue (39.6M locked MT tests),
//    ~61us fixed harness reset-dispatch overhead. At the roofline.

#define RX 0.4395064455f
#define RY 0.617598629942f
#define RZ 0.652231566745f

#define MAXCHUNK_F4 256   // LDS float4 slots; >= max(chunkA,chunkB)*4 (252)
#define PTS_PER_BLK 512   // 2 points per thread

struct Params {
    const float* hand_verts; const int* hand_faces;
    const float* obj_verts;  const int* obj_faces;
    const int* ovsplit; const int* ofsplit;
    int* hitsA;                // [B*No] pass-A hit counts (atomic accum)
    int* hitsB;                // [B*Nh] pass-B hit counts (atomic accum)
    float* anchor_h; float* anchor_o;
    float* partials;           // [B*16*6] per-(batch, virtual-wave) partials
    unsigned int* done;
    float* out;
    int B, Nh, Fh, No, Fo;
    int pbA, CA, chunkA, blocksA;
    int pbB, CB, chunkB, blocksB;
};

// ---------------------------------------------------------------------------
// Per-triangle precompute (absmax-0.0 lineage; valid folded into invdet=0 —
// R7/R9-validated bit-exact).
// ---------------------------------------------------------------------------
__device__ __forceinline__ void tri_pre_one(const float* __restrict__ vb,
                                            const int* __restrict__ f,
                                            float4* o) {
#pragma clang fp contract(off)
    int i0 = f[0], i1 = f[1], i2 = f[2];
    float v0x = vb[i0*3+0], v0y = vb[i0*3+1], v0z = vb[i0*3+2];
    float v1x = vb[i1*3+0], v1y = vb[i1*3+1], v1z = vb[i1*3+2];
    float v2x = vb[i2*3+0], v2y = vb[i2*3+1], v2z = vb[i2*3+2];
    float e1x = v1x - v0x, e1y = v1y - v0y, e1z = v1z - v0z;
    float e2x = v2x - v0x, e2y = v2y - v0y, e2z = v2z - v0z;
    float px = RY*e2z - RZ*e2y;
    float py = RZ*e2x - RX*e2z;
    float pz = RX*e2y - RY*e2x;
    float det = (e1x*px + e1y*py) + e1z*pz;       // ((a+b)+c) like np.sum
    float invdet = 1.0f / (det + 1e-8f);          // 0.1*TOL, IEEE div
    if (fabsf(det) < 1e-7f) invdet = 0.0f;        // parallel => no hit, exactly
    o[0] = make_float4(v0x, v0y, v0z, invdet);
    o[1] = make_float4(e1x, e1y, e1z, 0.0f);
    o[2] = make_float4(e2x, e2y, e2z, 0.0f);
    o[3] = make_float4(px,  py,  pz,  0.0f);
}

// One Möller–Trumbore test (expression tree identical to absmax-0.0 lineage).
__device__ __forceinline__ int mt_test(float qx, float qy, float qz,
                                       const float4& f0, const float4& f1,
                                       const float4& f2, const float4& f3) {
#pragma clang fp contract(off)
    float tvx = qx - f0.x, tvy = qy - f0.y, tvz = qz - f0.z;
    float u  = ((tvx*f3.x + tvy*f3.y) + tvz*f3.z) * f0.w;
    float qvx = tvy*f1.z - tvz*f1.y;
    float qvy = tvz*f1.x - tvx*f1.z;
    float qvz = tvx*f1.y - tvy*f1.x;
    float v  = ((qvx*RX + qvy*RY) + qvz*RZ) * f0.w;
    float tt = ((f2.x*qvx + f2.y*qvy) + f2.z*qvz) * f0.w;
    bool hit = (u > 0.0f) && (u < 1.0f) && (v > 0.0f) &&
               ((u + v) < 1.0f) && (tt > 1e-7f);
    return hit ? 1 : 0;
}

// ---------------------------------------------------------------------------
// One raycast virtual block: chunk staged in LDS, 2 points per thread,
// wave-uniform __any(act2) selection, atomic count accumulate.
// ---------------------------------------------------------------------------
__device__ __forceinline__ void raycast_vb(const Params& p, int vbid, int tid,
                                           float4* s_tri) {
#pragma clang fp contract(off)
    const float* pts; const float* tverts; const int* tfaces; int* slots;
    int P, T, Nv, c, pb, b, chunk, tlim, plim;
    if (vbid < p.blocksA) {
        int per_b = p.pbA * p.CA;
        b  = vbid / per_b;
        int r = vbid - b * per_b;
        c  = r / p.pbA;
        pb = r - c * p.pbA;
        pts = p.obj_verts; tverts = p.hand_verts; tfaces = p.hand_faces;
        slots = p.hitsA;
        P = p.No; T = p.Fh; Nv = p.Nh; chunk = p.chunkA;
        tlim = p.Fh; plim = min(p.No, p.ovsplit[b]);   // invalid pts never read
    } else {
        int j = vbid - p.blocksA;
        int per_b = p.pbB * p.CB;
        b  = j / per_b;
        int r = j - b * per_b;
        c  = r / p.pbB;
        pb = r - c * p.pbB;
        pts = p.hand_verts; tverts = p.obj_verts; tfaces = p.obj_faces;
        slots = p.hitsB;
        P = p.Nh; T = p.Fo; Nv = p.No; chunk = p.chunkB;
        tlim = min(p.Fo, p.ofsplit[b]); plim = p.Nh;
    }

    int tStart = c * chunk;
    if (tStart >= tlim) return;               // block-uniform
    if (pb * PTS_PER_BLK >= plim) return;     // block-uniform
    int nTri = min(tStart + chunk, tlim) - tStart;

    if (tid < nTri) {
        int t = tStart + tid;
        tri_pre_one(tverts + (size_t)b * Nv * 3,
                    tfaces + ((size_t)b * T + t) * 3,
                    s_tri + (size_t)tid * 4);
    }

    int p1 = pb * PTS_PER_BLK + tid;
    int p2 = p1 + 256;
    bool act1 = p1 < plim, act2 = p2 < plim;
    float q1x = 0.f, q1y = 0.f, q1z = 0.f;
    float q2x = 0.f, q2y = 0.f, q2z = 0.f;
    if (act1) {
        const float* q = pts + ((size_t)b * P + p1) * 3;
        q1x = q[0]; q1y = q[1]; q1z = q[2];
    }
    if (act2) {
        const float* q = pts + ((size_t)b * P + p2) * 3;
        q2x = q[0]; q2y = q[1]; q2z = q[2];
    }
    __syncthreads();

    if (!act1) return;                        // act1 false => act2 false
    int cnt1 = 0, cnt2 = 0;
    if (__any(act2)) {
        for (int i = 0; i < nTri; ++i) {
            const float4 f0 = s_tri[(i<<2)+0];
            const float4 f1 = s_tri[(i<<2)+1];
            const float4 f2 = s_tri[(i<<2)+2];
            const float4 f3 = s_tri[(i<<2)+3];
            cnt1 += mt_test(q1x, q1y, q1z, f0, f1, f2, f3);
            cnt2 += mt_test(q2x, q2y, q2z, f0, f1, f2, f3);
        }
    } else {
        for (int i = 0; i < nTri; ++i) {
            const float4 f0 = s_tri[(i<<2)+0];
            const float4 f1 = s_tri[(i<<2)+1];
            const float4 f2 = s_tri[(i<<2)+2];
            const float4 f3 = s_tri[(i<<2)+3];
            cnt1 += mt_test(q1x, q1y, q1z, f0, f1, f2, f3);
        }
    }
    int* base = slots + (size_t)b * P;
    if (cnt1)         atomicAdd(&base[p1], cnt1);   // integer sum — exact
    if (act2 && cnt2) atomicAdd(&base[p2], cnt2);
}

// ---------------------------------------------------------------------------
// One argmin wave. Packed (dist<<32)|idx min => np.argmin tie-break.
// ---------------------------------------------------------------------------
__device__ __forceinline__ void min_one(const Params& p, int w, int lane) {
#pragma clang fp contract(off)
    int nHand = p.B * p.Nh;
    const float* refv; const float* loopv; int loopN; float* outp;
    if (w < nHand) {
        int b = w / p.Nh;
        int n = w - b * p.Nh;
        refv  = p.hand_verts + ((size_t)b * p.Nh + n) * 3;
        loopv = p.obj_verts + (size_t)b * p.No * 3;
        loopN = p.ovsplit[b];
        outp  = p.anchor_h + (size_t)b * p.Nh + n;
    } else {
        int j = w - nHand;
        int b = j / p.No;
        int m = j - b * p.No;
        if (m >= p.ovsplit[b]) return;
        refv  = p.obj_verts + ((size_t)b * p.No + m) * 3;
        loopv = p.hand_verts + (size_t)b * p.Nh * 3;
        loopN = p.Nh;
        outp  = p.anchor_o + (size_t)b * p.No + m;
    }
    float hx = refv[0], hy = refv[1], hz = refv[2];
    float rx = (hx*hx + hy*hy) + hz*hz;
    unsigned long long best = ~0ull;
    for (int m = lane; m < loopN; m += 64) {
        float ox = loopv[m*3+0], oy = loopv[m*3+1], oz = loopv[m*3+2];
        float ry = (ox*ox + oy*oy) + oz*oz;
        float zz = (hx*ox + hy*oy) + hz*oz;
        float d = (rx + ry) - 2.0f * zz;
        unsigned long long e = ((unsigned long long)__float_as_uint(d) << 32) | (unsigned)m;
        if (e < best) best = e;
    }
    for (int off = 32; off > 0; off >>= 1) {
        unsigned long long o = __shfl_xor(best, off, 64);
        if (o < best) best = o;
    }
    if (lane == 0) {
        int idx = (best == ~0ull) ? 0 : (int)(best & 0xffffffffu);
        const float* cv = loopv + (size_t)idx * 3;
        float dx = cv[0] - hx, dy = cv[1] - hy, dz = cv[2] - hz;
        *outp = sqrtf((dx*dx + dy*dy) + dz*dz);
    }
}

// ---------------------------------------------------------------------------
// mega: [raycast VBs | argmin blocks] — no tail sync; resets done counter.
// ---------------------------------------------------------------------------
__global__ __launch_bounds__(256) void mega(Params p) {
    __shared__ float4 s_tri[MAXCHUNK_F4];
    const int tid = threadIdx.x;
    const int bid = blockIdx.x;
    if (bid == 0 && tid == 0) *p.done = 0u;   // visible to reduce_fin at boundary
    const int nRay = p.blocksA + p.blocksB;
    if (bid < nRay) {
        raycast_vb(p, bid, tid, s_tri);
    } else {
        int w = (bid - nRay) * 4 + (tid >> 6);
        if (w < p.B * (p.Nh + p.No)) min_one(p, w, tid & 63);
    }
}

// ---------------------------------------------------------------------------
// reduce_fin: 128 single-wave blocks. Parity = 1 load/point. (batch,
// virtual-wave) bit-exact tree; done-counter + fence finalize.
// ---------------------------------------------------------------------------
__global__ __launch_bounds__(64) void reduce_fin(Params p) {
    const int r    = blockIdx.x;
    const int b    = r >> 4;
    const int wv   = r & 15;
    const int lane = threadIdx.x;
    const int vt   = wv * 64 + lane;          // virtual tid 0..1023
    float s0=0.f,s1=0.f,s2=0.f,s3=0.f,s4=0.f,s5=0.f;

    for (int n = vt; n < p.Nh; n += 1024) {
        int par = p.hitsB[(size_t)b * p.Nh + n];
        bool ext = (par & 1) == 0;
        float val = 25.0f * tanhf(p.anchor_h[(size_t)b*p.Nh + n] / 25.0f);
        if (ext) { s0 += val; s1 += 1.0f; } else { s2 += val; s3 += 1.0f; }
    }
    int split = p.ovsplit[b];
    for (int m = vt; m < split; m += 1024) {
        int par = p.hitsA[(size_t)b * p.No + m];
        if (par & 1) {                                   // interior & valid
            s4 += 25.0f * tanhf(p.anchor_o[(size_t)b*p.No + m] / 25.0f);
            s5 += 1.0f;
        }
    }
    for (int off = 32; off > 0; off >>= 1) {
        s0 += __shfl_xor(s0, off, 64);
        s1 += __shfl_xor(s1, off, 64);
        s2 += __shfl_xor(s2, off, 64);
        s3 += __shfl_xor(s3, off, 64);
        s4 += __shfl_xor(s4, off, 64);
        s5 += __shfl_xor(s5, off, 64);
    }

    __shared__ bool s_last;
    if (lane == 0) {
        float* q = p.partials + ((size_t)(b * 16 + wv)) * 6;
        q[0]=s0; q[1]=s1; q[2]=s2; q[3]=s3; q[4]=s4; q[5]=s5;
        __threadfence();                     // release partials
        unsigned int old = atomicAdd(p.done, 1u);
        s_last = (old == (unsigned int)(gridDim.x - 1));
    }
    __syncthreads();
    if (!s_last) return;
    __threadfence();                         // acquire others' partials

    __shared__ float s_red[16][6];
    if (lane < p.B && lane < 16) {
        int bb = lane;
        float t0=0.f,t1=0.f,t2=0.f,t3=0.f,t4=0.f,t5=0.f;
        for (int w2 = 0; w2 < 16; ++w2) {     // same wave order as old loop
            const float* q = p.partials + ((size_t)(bb * 16 + w2)) * 6;
            t0 += q[0]; t1 += q[1]; t2 += q[2];
            t3 += q[3]; t4 += q[4]; t5 += q[5];
        }
        p.out[2 + bb]  = (t1 > 0.f) ? t0 / fmaxf(t1, 1.f) : 0.f;
        float ph       = (t3 > 0.f) ? t2 / fmaxf(t3, 1.f) : 0.f;
        float po       = (t5 > 0.f) ? t4 / fmaxf(t5, 1.f) : 0.f;
        p.out[10 + bb] = ph + po;
        s_red[bb][0]=t0; s_red[bb][1]=t1; s_red[bb][2]=t2;
        s_red[bb][3]=t3; s_red[bb][4]=t4; s_red[bb][5]=t5;
    }
    __syncthreads();
    if (lane == 0) {
        float sm=0.f,cm=0.f,sph=0.f,cph=0.f,spo=0.f,cpo=0.f;
        for (int bb = 0; bb < p.B; ++bb) {    // same batch order as old final
            sm  += s_red[bb][0]; cm  += s_red[bb][1]; sph += s_red[bb][2];
            cph += s_red[bb][3]; spo += s_red[bb][4]; cpo += s_red[bb][5];
        }
        float missed = (cm  > 0.f) ? sm  / fmaxf(cm , 1.f) : 0.f;
        float ph     = (cph > 0.f) ? sph / fmaxf(cph, 1.f) : 0.f;
        float po     = (cpo > 0.f) ? spo / fmaxf(cpo, 1.f) : 0.f;
        p.out[0] = missed;
        p.out[1] = ph + po;
    }
}

// ---------------------------------------------------------------------------
extern "C" void kernel_launch(void* const* d_in, const int* in_sizes, int n_in,
                              void* d_out, int out_size, void* d_ws, size_t ws_size,
                              hipStream_t stream) {
    Params p;
    p.hand_verts = (const float*)d_in[0];
    p.hand_faces = (const int*)d_in[1];
    p.obj_verts  = (const float*)d_in[2];
    p.obj_faces  = (const int*)d_in[3];
    p.ovsplit    = (const int*)d_in[4];
    p.ofsplit    = (const int*)d_in[5];
    p.out        = (float*)d_out;

    p.B  = in_sizes[4];
    p.Nh = in_sizes[0] / (3 * p.B);
    p.Fh = in_sizes[1] / (3 * p.B);
    p.No = in_sizes[2] / (3 * p.B);
    p.Fo = in_sizes[3] / (3 * p.B);

    p.CA = 32; p.CB = 64;
    p.chunkA = (p.Fh + p.CA - 1) / p.CA;       // 49 for Fh=1538
    p.chunkB = (p.Fo + p.CB - 1) / p.CB;       // 63 for Fo=4000
    p.pbA = (p.No + PTS_PER_BLK - 1) / PTS_PER_BLK;   // 4
    p.pbB = (p.Nh + PTS_PER_BLK - 1) / PTS_PER_BLK;   // 2
    p.blocksA = p.pbA * p.CA * p.B;            // 1024
    p.blocksB = p.pbB * p.CB * p.B;            // 1024

    char* ws = (char*)d_ws;
    size_t off = 0;
    auto alloc = [&](size_t bytes) -> void* {
        void* q = ws + off;
        off = (off + bytes + 255) & ~(size_t)255;
        return q;
    };
    size_t hitsOff = off;
    p.hitsA    = (int*)   alloc((size_t)p.B * p.No * sizeof(int));
    p.hitsB    = (int*)   alloc((size_t)p.B * p.Nh * sizeof(int));
    size_t hitsBytes = off - hitsOff;          // contiguous span, one memset
    p.anchor_h = (float*) alloc((size_t)p.B * p.Nh * sizeof(float));
    p.anchor_o = (float*) alloc((size_t)p.B * p.No * sizeof(float));
    p.partials = (float*) alloc((size_t)p.B * 16 * 6 * sizeof(float));
    p.done     = (unsigned int*)alloc(sizeof(unsigned int));

    int totalMin   = p.B * (p.Nh + p.No);
    int nMinBlocks = (totalMin + 3) / 4;       // 4 argmin waves per block
    int grid = p.blocksA + p.blocksB + nMinBlocks;

    hipMemsetAsync((void*)p.hitsA, 0, hitsBytes, stream);
    mega<<<grid, 256, 0, stream>>>(p);
    reduce_fin<<<p.B * 16, 64, 0, stream>>>(p);
}